// Round 12
// baseline (66.064 us; speedup 1.0000x reference)
//
#include <hip/hip_runtime.h>
#include <stdint.h>
#include <math.h>

// CategoricalSampler: argmax_v( logits[b,s,v]*(log2e/T) + g2(v) ), g2 = -log2(-log2 u),
// u from JAX threefry2x32-20 partitionable path: bits[i] = x0^x1, key=(0,42), ctr=(0, i).
// Bit-scheme verified R2; value path verified R3/R5-R11 (absmax=0).
//
// R4: no cancellation forms in the log path. R8/R9: compiler ignores source-level
// scheduling; only instruction removal pays. R10: raw-bits candidate filter (u>=tau
// <=> bits>=B0; candidate set is data-INDEPENDENT, fixed by key) + stage2 bound check
// with exact full-row fallback. R11: asm v_alignbit rotates (proved already-1-inst),
// uniform 5-blocks/CU grid. R12: occupancy 20->25 waves/CU (TPB=320, J=20 exact),
// isolating wave-count as the issue-efficiency lever.

constexpr int V = 128000;
constexpr int NROWS = 256;       // B*S
constexpr int TPB = 320;         // 5 waves/block
constexpr int SPLIT = 5;         // grid 1280 = 5 blocks/CU exactly -> 25 waves/CU uniform
constexpr int SEG = V / SPLIT;   // 25600
constexpr int J = SEG / (TPB * 4);  // 20 exact

// tau ~ 0.996: B0 = ceil(0.996*2^23)<<9. Skipped elems: g2 <= 7.4342 < G2TAU.
// P(row winner below bound) ~ 3e-7 analytically; fallback is exact rescan anyway.
constexpr uint32_t B0 = 8355054u << 9;
#define G2TAU 7.44f

// Forced single-instruction rotate: rotl(x,r) == v_alignbit_b32(x, x, 32-r).
template <uint32_t R>
__device__ __forceinline__ uint32_t rotl_(uint32_t x) {
  uint32_t d;
  asm("v_alignbit_b32 %0, %1, %1, %2" : "=v"(d) : "v"(x), "n"(32u - R));
  return d;
}

// Threefry-2x32-20, key (0,42), counter (0, ctr). Input c = ctr + 42 (ks1 pre-added).
// ks0=0, ks1=42, ks2=0x1BD11BDA^42=0x1BD11BF0. Round-1 mov folded: x0_r1 = c.
__device__ __forceinline__ uint32_t threefry_xor_pre(uint32_t c) {
  uint32_t x1 = rotl_<13>(c) ^ c;       // round 1 (x0 = 0 + c)
  uint32_t x0 = c + x1;                 // round 2
  x1 = rotl_<15>(x1) ^ x0;
  x0 += x1; x1 = rotl_<26>(x1) ^ x0;
  x0 += x1; x1 = rotl_< 6>(x1) ^ x0;
  x1 += 0x1BD11BF1u; x0 = x0 + 42u + x1;         // inject1 (ks1 | ks2+1)
  x1 = rotl_<17>(x1) ^ x0;
  x0 += x1; x1 = rotl_<29>(x1) ^ x0;
  x0 += x1; x1 = rotl_<16>(x1) ^ x0;
  x0 += x1; x1 = rotl_<24>(x1) ^ x0;
  x1 += 2u; x0 = x0 + 0x1BD11BF0u + x1;          // inject2 (ks2 | ks0+2)
  x1 = rotl_<13>(x1) ^ x0;
  x0 += x1; x1 = rotl_<15>(x1) ^ x0;
  x0 += x1; x1 = rotl_<26>(x1) ^ x0;
  x0 += x1; x1 = rotl_< 6>(x1) ^ x0;
  x1 += 45u; x0 += x1;                           // inject3 (ks0=0 | ks1+3)
  x1 = rotl_<17>(x1) ^ x0;
  x0 += x1; x1 = rotl_<29>(x1) ^ x0;
  x0 += x1; x1 = rotl_<16>(x1) ^ x0;
  x0 += x1; x1 = rotl_<24>(x1) ^ x0;
  x1 += 0x1BD11BF4u; x0 = x0 + 42u + x1;         // inject4 (ks1 | ks2+4)
  x1 = rotl_<13>(x1) ^ x0;
  x0 += x1; x1 = rotl_<15>(x1) ^ x0;
  x0 += x1; x1 = rotl_<26>(x1) ^ x0;
  x0 += x1; x1 = rotl_< 6>(x1) ^ x0;
  return (x0 + 0x1BD11BF0u) ^ (x1 + 5u);         // inject5 (ks2 | ks0+5) folded
}

__device__ __forceinline__ uint32_t mant_pack(uint32_t bits) {
#if __has_builtin(__builtin_amdgcn_alignbit)
  return __builtin_amdgcn_alignbit(127u, bits, 9u);  // (bits>>9)|0x3f800000
#else
  return (bits >> 9) | 0x3f800000u;
#endif
}

__device__ __forceinline__ float gval(uint32_t bits, float l, float scale) {
  const float u  = __uint_as_float(mant_pack(bits)) - 1.0f;  // [0,1); 0 -> -inf, loses
  const float s1 = __log2f(u);
  const float s2 = __log2f(-s1);          // g2 = -s2 (neg folds to VOP3 modifier)
  return fmaf(l, scale, -s2);
}

__global__ __launch_bounds__(TPB) void CategoricalSampler_stage1(
    const float* __restrict__ logits, const float* __restrict__ temp,
    float2* __restrict__ ws1, float* __restrict__ wsl) {
  const int b   = blockIdx.x;
  const int row = b / SPLIT;
  const int seg = b - row * SPLIT;
  const int t   = threadIdx.x;
  const float scale = 1.4426950408889634f / temp[0];
  const int segbase = seg * SEG;
  const float4* rp4 = reinterpret_cast<const float4*>(logits + (size_t)row * V + segbase);
  const uint32_t cb42 = (uint32_t)row * (uint32_t)V + (uint32_t)segbase
                      + (uint32_t)(t * 4) + 42u;

  float best = -INFINITY;
  int bestCode = 0;
  float lmax = -INFINITY;

#pragma unroll 5
  for (int j = 0; j < J; ++j) {
    const float4 L = rp4[j * TPB + t];
    lmax = fmaxf(lmax, fmaxf(fmaxf(L.x, L.y), fmaxf(L.z, L.w)));
    const uint32_t c0 = cb42 + (uint32_t)(j * TPB * 4);
#pragma unroll
    for (int k = 0; k < 4; ++k) {
      const uint32_t bits = threefry_xor_pre(c0 + (uint32_t)k);
      if (bits >= B0) {                        // candidate: u >= ~0.996 (wave-rare)
        const float lk = (k == 0) ? L.x : (k == 1) ? L.y : (k == 2) ? L.z : L.w;
        const float val = gval(bits, lk, scale);
        if (val > best) { best = val; bestCode = j * 4 + k; }
      }
    }
  }

  // reconstruct global index: v = segbase + j*TPB*4 + t*4 + k
  int bestIdx = segbase + (bestCode >> 2) * (TPB * 4) + (t << 2) + (bestCode & 3);

  // wave reduce: max val (earliest index on ties) and max logit
#pragma unroll
  for (int off = 32; off > 0; off >>= 1) {
    const float ov = __shfl_down(best, off);
    const int   oi = __shfl_down(bestIdx, off);
    const float ol = __shfl_down(lmax, off);
    if (ov > best || (ov == best && oi < bestIdx)) { best = ov; bestIdx = oi; }
    lmax = fmaxf(lmax, ol);
  }

  __shared__ float sv[TPB / 64];
  __shared__ int   si[TPB / 64];
  __shared__ float sl[TPB / 64];
  const int wid = t >> 6;
  if ((t & 63) == 0) { sv[wid] = best; si[wid] = bestIdx; sl[wid] = lmax; }
  __syncthreads();
  if (t == 0) {
    float fv = sv[0]; int fi = si[0]; float fl = sl[0];
#pragma unroll
    for (int w = 1; w < TPB / 64; ++w) {
      if (sv[w] > fv || (sv[w] == fv && si[w] < fi)) { fv = sv[w]; fi = si[w]; }
      fl = fmaxf(fl, sl[w]);
    }
    ws1[b] = make_float2(fv, __int_as_float(fi));
    wsl[b] = fl;
  }
}

// Stage 2: combine segments; verify winner beats the skip-bound; exact full-row
// re-scan on the (deterministic, ~never) failure.
__global__ __launch_bounds__(64) void CategoricalSampler_stage2(
    const float2* __restrict__ ws1, const float* __restrict__ wsl,
    const float* __restrict__ logits, const float* __restrict__ temp,
    int* __restrict__ out) {
  const int r = blockIdx.x;
  const int l = threadIdx.x;
  const float scale = 1.4426950408889634f / temp[0];
  float best = -INFINITY; int bestIdx = 0x7FFFFFFF; float lmax = -INFINITY;
  if (l < SPLIT) {
    const float2 p = ws1[r * SPLIT + l];
    best = p.x; bestIdx = __float_as_int(p.y);
    lmax = wsl[r * SPLIT + l];
  }
#pragma unroll
  for (int off = 32; off > 0; off >>= 1) {
    const float ov = __shfl_down(best, off);
    const int   oi = __shfl_down(bestIdx, off);
    const float ol = __shfl_down(lmax, off);
    if (ov > best || (ov == best && oi < bestIdx)) { best = ov; bestIdx = oi; }
    lmax = fmaxf(lmax, ol);
  }
  best = __shfl(best, 0); bestIdx = __shfl(bestIdx, 0); lmax = __shfl(lmax, 0);
  const float bound = fmaf(lmax, scale, G2TAU);   // upper bound on any skipped val
  if (best >= bound) {
    if (l == 0) out[r] = bestIdx;
    return;
  }
  // Fallback: exact full-row scan by this wave (bit-identical math).
  const uint32_t cb42 = (uint32_t)r * (uint32_t)V + 42u;
  const float* rowp = logits + (size_t)r * V;
  float fb = -INFINITY; int fi = 0;
  for (int v = l; v < V; v += 64) {
    const uint32_t bits = threefry_xor_pre(cb42 + (uint32_t)v);
    const float val = gval(bits, rowp[v], scale);
    if (val > fb) { fb = val; fi = v; }
  }
#pragma unroll
  for (int off = 32; off > 0; off >>= 1) {
    const float ov = __shfl_down(fb, off);
    const int   oi = __shfl_down(fi, off);
    if (ov > fb || (ov == fb && oi < fi)) { fb = ov; fi = oi; }
  }
  if (l == 0) out[r] = fi;
}

extern "C" void kernel_launch(void* const* d_in, const int* in_sizes, int n_in,
                              void* d_out, int out_size, void* d_ws, size_t ws_size,
                              hipStream_t stream) {
  const float* logits = (const float*)d_in[0];
  const float* temp   = (const float*)d_in[1];
  int* out = (int*)d_out;
  float2* ws1 = (float2*)d_ws;                   // 1280 float2
  float*  wsl = (float*)(ws1 + NROWS * SPLIT);   // 1280 float  (total 15.4 KB)
  CategoricalSampler_stage1<<<NROWS * SPLIT, TPB, 0, stream>>>(logits, temp, ws1, wsl);
  CategoricalSampler_stage2<<<NROWS, 64, 0, stream>>>(ws1, wsl, logits, temp, out);
}

// Round 13
// 61.197 us; speedup vs baseline: 1.0795x; 1.0795x over previous
//
#include <hip/hip_runtime.h>
#include <stdint.h>
#include <math.h>

// CategoricalSampler: argmax_v( logits[b,s,v]*(log2e/T) + g2(v) ), g2 = -log2(-log2 u),
// u from JAX threefry2x32-20 partitionable path: bits[i] = x0^x1, key=(0,42), ctr=(0, i).
// Bit-scheme verified R2; value path verified R3/R5-R12 (absmax=0).
//
// R4: no cancellation in the log path. R8/R9: compiler ignores source scheduling; ILP
// batching hurts. R10: raw-bits filter (bits>=B0 <=> u>=~0.996) + stage2 bound check
// with exact full-row fallback. R11: asm alignbit rotates; uniform 5 blocks/CU = 62 us.
// R12: 25 waves/CU IMBALANCED (7/6/6/6) regressed per-imbalance-model; waves helped ~3.5us.
// R13: max uniform occupancy — SPLIT=8, TPB=256, grid 2048 = 8 blocks/CU = 32 waves/CU,
// 8 waves/SIMD uniform. SEG=16000 -> 15 float4 groups/thread + tail group for t<160.

constexpr int V = 128000;
constexpr int NROWS = 256;       // B*S
constexpr int TPB = 256;
constexpr int SPLIT = 8;         // grid 2048 = 8 blocks/CU exactly -> 32 waves/CU uniform
constexpr int SEG = V / SPLIT;   // 16000
constexpr int JF = 15;           // full float4 groups per thread (15*256*4 = 15360)
constexpr int TAILT = (SEG - JF * TPB * 4) / 4;  // 160 threads take one extra group

// tau ~ 0.996: B0 = ceil(0.996*2^23)<<9. Skipped elems: g2 <= 7.4342 < G2TAU.
constexpr uint32_t B0 = 8355054u << 9;
#define G2TAU 7.44f

// Forced single-instruction rotate: rotl(x,r) == v_alignbit_b32(x, x, 32-r).
template <uint32_t R>
__device__ __forceinline__ uint32_t rotl_(uint32_t x) {
  uint32_t d;
  asm("v_alignbit_b32 %0, %1, %1, %2" : "=v"(d) : "v"(x), "n"(32u - R));
  return d;
}

// Threefry-2x32-20, key (0,42), counter (0, ctr). Input c = ctr + 42 (ks1 pre-added).
// ks0=0, ks1=42, ks2=0x1BD11BDA^42=0x1BD11BF0. Round-1 mov folded: x0_r1 = c.
__device__ __forceinline__ uint32_t threefry_xor_pre(uint32_t c) {
  uint32_t x1 = rotl_<13>(c) ^ c;       // round 1 (x0 = 0 + c)
  uint32_t x0 = c + x1;                 // round 2
  x1 = rotl_<15>(x1) ^ x0;
  x0 += x1; x1 = rotl_<26>(x1) ^ x0;
  x0 += x1; x1 = rotl_< 6>(x1) ^ x0;
  x1 += 0x1BD11BF1u; x0 = x0 + 42u + x1;         // inject1 (ks1 | ks2+1)
  x1 = rotl_<17>(x1) ^ x0;
  x0 += x1; x1 = rotl_<29>(x1) ^ x0;
  x0 += x1; x1 = rotl_<16>(x1) ^ x0;
  x0 += x1; x1 = rotl_<24>(x1) ^ x0;
  x1 += 2u; x0 = x0 + 0x1BD11BF0u + x1;          // inject2 (ks2 | ks0+2)
  x1 = rotl_<13>(x1) ^ x0;
  x0 += x1; x1 = rotl_<15>(x1) ^ x0;
  x0 += x1; x1 = rotl_<26>(x1) ^ x0;
  x0 += x1; x1 = rotl_< 6>(x1) ^ x0;
  x1 += 45u; x0 += x1;                           // inject3 (ks0=0 | ks1+3)
  x1 = rotl_<17>(x1) ^ x0;
  x0 += x1; x1 = rotl_<29>(x1) ^ x0;
  x0 += x1; x1 = rotl_<16>(x1) ^ x0;
  x0 += x1; x1 = rotl_<24>(x1) ^ x0;
  x1 += 0x1BD11BF4u; x0 = x0 + 42u + x1;         // inject4 (ks1 | ks2+4)
  x1 = rotl_<13>(x1) ^ x0;
  x0 += x1; x1 = rotl_<15>(x1) ^ x0;
  x0 += x1; x1 = rotl_<26>(x1) ^ x0;
  x0 += x1; x1 = rotl_< 6>(x1) ^ x0;
  return (x0 + 0x1BD11BF0u) ^ (x1 + 5u);         // inject5 (ks2 | ks0+5) folded
}

__device__ __forceinline__ uint32_t mant_pack(uint32_t bits) {
#if __has_builtin(__builtin_amdgcn_alignbit)
  return __builtin_amdgcn_alignbit(127u, bits, 9u);  // (bits>>9)|0x3f800000
#else
  return (bits >> 9) | 0x3f800000u;
#endif
}

__device__ __forceinline__ float gval(uint32_t bits, float l, float scale) {
  const float u  = __uint_as_float(mant_pack(bits)) - 1.0f;  // [0,1); 0 -> -inf, loses
  const float s1 = __log2f(u);
  const float s2 = __log2f(-s1);          // g2 = -s2 (neg folds to VOP3 modifier)
  return fmaf(l, scale, -s2);
}

__global__ __launch_bounds__(TPB) void CategoricalSampler_stage1(
    const float* __restrict__ logits, const float* __restrict__ temp,
    float2* __restrict__ ws1, float* __restrict__ wsl) {
  const int b   = blockIdx.x;
  const int row = b >> 3;              // SPLIT = 8
  const int seg = b & 7;
  const int t   = threadIdx.x;
  const float scale = 1.4426950408889634f / temp[0];
  const int segbase = seg * SEG;
  const float4* rp4 = reinterpret_cast<const float4*>(logits + (size_t)row * V + segbase);
  const uint32_t cb42 = (uint32_t)row * (uint32_t)V + (uint32_t)segbase
                      + (uint32_t)(t * 4) + 42u;

  float best = -INFINITY;
  int bestCode = 0;
  float lmax = -INFINITY;

#pragma unroll 5
  for (int j = 0; j < JF; ++j) {
    const float4 L = rp4[j * TPB + t];
    lmax = fmaxf(lmax, fmaxf(fmaxf(L.x, L.y), fmaxf(L.z, L.w)));
    const uint32_t c0 = cb42 + (uint32_t)(j * TPB * 4);
#pragma unroll
    for (int k = 0; k < 4; ++k) {
      const uint32_t bits = threefry_xor_pre(c0 + (uint32_t)k);
      if (bits >= B0) {                        // candidate: u >= ~0.996 (wave-rare)
        const float lk = (k == 0) ? L.x : (k == 1) ? L.y : (k == 2) ? L.z : L.w;
        const float val = gval(bits, lk, scale);
        if (val > best) { best = val; bestCode = j * 4 + k; }
      }
    }
  }
  // tail group: threads 0..TAILT-1 own one more float4 (uniform math, masked lanes)
  if (t < TAILT) {
    const float4 L = rp4[JF * TPB + t];
    lmax = fmaxf(lmax, fmaxf(fmaxf(L.x, L.y), fmaxf(L.z, L.w)));
    const uint32_t c0 = cb42 + (uint32_t)(JF * TPB * 4);
#pragma unroll
    for (int k = 0; k < 4; ++k) {
      const uint32_t bits = threefry_xor_pre(c0 + (uint32_t)k);
      if (bits >= B0) {
        const float lk = (k == 0) ? L.x : (k == 1) ? L.y : (k == 2) ? L.z : L.w;
        const float val = gval(bits, lk, scale);
        if (val > best) { best = val; bestCode = JF * 4 + k; }
      }
    }
  }

  // reconstruct global index: v = segbase + j*TPB*4 + t*4 + k
  int bestIdx = segbase + (bestCode >> 2) * (TPB * 4) + (t << 2) + (bestCode & 3);

  // wave reduce: max val (earliest index on ties) and max logit
#pragma unroll
  for (int off = 32; off > 0; off >>= 1) {
    const float ov = __shfl_down(best, off);
    const int   oi = __shfl_down(bestIdx, off);
    const float ol = __shfl_down(lmax, off);
    if (ov > best || (ov == best && oi < bestIdx)) { best = ov; bestIdx = oi; }
    lmax = fmaxf(lmax, ol);
  }

  __shared__ float sv[TPB / 64];
  __shared__ int   si[TPB / 64];
  __shared__ float sl[TPB / 64];
  const int wid = t >> 6;
  if ((t & 63) == 0) { sv[wid] = best; si[wid] = bestIdx; sl[wid] = lmax; }
  __syncthreads();
  if (t == 0) {
    float fv = sv[0]; int fi = si[0]; float fl = sl[0];
#pragma unroll
    for (int w = 1; w < TPB / 64; ++w) {
      if (sv[w] > fv || (sv[w] == fv && si[w] < fi)) { fv = sv[w]; fi = si[w]; }
      fl = fmaxf(fl, sl[w]);
    }
    ws1[b] = make_float2(fv, __int_as_float(fi));
    wsl[b] = fl;
  }
}

// Stage 2: combine segments; verify winner beats the skip-bound; exact full-row
// re-scan on the (deterministic, ~never) failure.
__global__ __launch_bounds__(64) void CategoricalSampler_stage2(
    const float2* __restrict__ ws1, const float* __restrict__ wsl,
    const float* __restrict__ logits, const float* __restrict__ temp,
    int* __restrict__ out) {
  const int r = blockIdx.x;
  const int l = threadIdx.x;
  const float scale = 1.4426950408889634f / temp[0];
  float best = -INFINITY; int bestIdx = 0x7FFFFFFF; float lmax = -INFINITY;
  if (l < SPLIT) {
    const float2 p = ws1[r * SPLIT + l];
    best = p.x; bestIdx = __float_as_int(p.y);
    lmax = wsl[r * SPLIT + l];
  }
#pragma unroll
  for (int off = 32; off > 0; off >>= 1) {
    const float ov = __shfl_down(best, off);
    const int   oi = __shfl_down(bestIdx, off);
    const float ol = __shfl_down(lmax, off);
    if (ov > best || (ov == best && oi < bestIdx)) { best = ov; bestIdx = oi; }
    lmax = fmaxf(lmax, ol);
  }
  best = __shfl(best, 0); bestIdx = __shfl(bestIdx, 0); lmax = __shfl(lmax, 0);
  const float bound = fmaf(lmax, scale, G2TAU);   // upper bound on any skipped val
  if (best >= bound) {
    if (l == 0) out[r] = bestIdx;
    return;
  }
  // Fallback: exact full-row scan by this wave (bit-identical math).
  const uint32_t cb42 = (uint32_t)r * (uint32_t)V + 42u;
  const float* rowp = logits + (size_t)r * V;
  float fb = -INFINITY; int fi = 0;
  for (int v = l; v < V; v += 64) {
    const uint32_t bits = threefry_xor_pre(cb42 + (uint32_t)v);
    const float val = gval(bits, rowp[v], scale);
    if (val > fb) { fb = val; fi = v; }
  }
#pragma unroll
  for (int off = 32; off > 0; off >>= 1) {
    const float ov = __shfl_down(fb, off);
    const int   oi = __shfl_down(fi, off);
    if (ov > fb || (ov == fb && oi < fi)) { fb = ov; fi = oi; }
  }
  if (l == 0) out[r] = fi;
}

extern "C" void kernel_launch(void* const* d_in, const int* in_sizes, int n_in,
                              void* d_out, int out_size, void* d_ws, size_t ws_size,
                              hipStream_t stream) {
  const float* logits = (const float*)d_in[0];
  const float* temp   = (const float*)d_in[1];
  int* out = (int*)d_out;
  float2* ws1 = (float2*)d_ws;                   // 2048 float2
  float*  wsl = (float*)(ws1 + NROWS * SPLIT);   // 2048 float  (total 24.6 KB)
  CategoricalSampler_stage1<<<NROWS * SPLIT, TPB, 0, stream>>>(logits, temp, ws1, wsl);
  CategoricalSampler_stage2<<<NROWS, 64, 0, stream>>>(ws1, wsl, logits, temp, out);
}